// Round 6
// baseline (209.767 us; speedup 1.0000x reference)
//
#include <hip/hip_runtime.h>
#include <math.h>

#define V_SIZE  100000
#define E_DIM   128
#define B_SIZE  512
#define Q_LEN   32
#define D_LEN   256
#define K_NUM   21
#define PHI_STR 24    // padded k-stride in the global phi buffer

// Kernel params (faithful to the reference's swapped sigma call):
// mus ascending: [-0.95, -0.85, ..., 0.85, 0.95, 1.0]
// sigmas descending: [0.1, 0.001 x 20]  -> k=0 broad (mu=-0.95), k>=1 sharp.
//
// Nearest-bin exactness: sharp sigma=1e-3 -> exp underflows to 0.0f once
// |mm-mu| > 0.01443; sharp mus are >=0.05 apart -> at most ONE sharp bin
// nonzero per mm. broad + nearest-sharp == all 21 bins (R2-R5: absmax 0).
//
// fp16-split matmul: a = hi + lo (both fp16); hi*hi + lo*hi + hi*lo drops only
// lo*lo (<=2^-22|a||b|) -> mm error ~1e-6 (R3-R5: absmax 0).
//
// R6: R5 structure, but __launch_bounds__(256, 8). R5's (256,4) capped
// residency at 4 blocks/CU -- the 2048-block split gained nothing. VGPR=60
// measured in R5 fits the 64-reg budget of 8 waves/EU, and LDS 19.5KB x 8 =
// 155.6KB <= 160KB. sched_barrier removed (did nothing; TLP does the hiding).

typedef _Float16 half8_t  __attribute__((ext_vector_type(8)));
typedef float    float4_t __attribute__((ext_vector_type(4)));

__global__ __launch_bounds__(256, 8) void knrm_gemm(
    const float* __restrict__ emb,
    const int* __restrict__ q1, const int* __restrict__ d1,
    const int* __restrict__ q2, const int* __restrict__ d2,
    float* __restrict__ phis_g)
{
    const int b     = blockIdx.x;
    const int pair  = blockIdx.y;
    const int split = blockIdx.z;
    const int t     = threadIdx.x;           // 0..255
    const int* __restrict__ qidx = pair ? q2 : q1;
    const int* __restrict__ didx = pair ? d2 : d1;

    __shared__ half8_t AfH[2][4][64];        // [qt][s][lane] query hi fragments
    __shared__ half8_t AfL[2][4][64];        // lo fragments
    __shared__ float rnq[Q_LEN];
    __shared__ float phis[Q_LEN][22];

    const int lane = t & 63;
    const int w    = t >> 6;                 // wave 0..3
    const int quad = lane >> 4;
    const int l15  = lane & 15;

    for (int i = t; i < Q_LEN * 22; i += 256) ((float*)phis)[i] = 0.f;

    // ---- doc gathers: wave owns docs dbase..dbase+31 (two 16x16 B tiles)
    const int dbase = split * 128 + w * 32;
    int di0 = didx[b * D_LEN + dbase + l15];
    int di1 = didx[b * D_LEN + dbase + 16 + l15];
    di0 = min(max(di0, 0), V_SIZE - 1);
    di1 = min(max(di1, 0), V_SIZE - 1);
    const float4* dr0 = (const float4*)(emb + (size_t)di0 * E_DIM) + quad * 2;
    const float4* dr1 = (const float4*)(emb + (size_t)di1 * E_DIM) + quad * 2;
    float4 raw0[8], raw1[8];
    #pragma unroll
    for (int s = 0; s < 4; ++s) {
        raw0[2*s]   = dr0[s*8];
        raw0[2*s+1] = dr0[s*8+1];
        raw1[2*s]   = dr1[s*8];
        raw1[2*s+1] = dr1[s*8+1];
    }

    // ---- query phase (overlaps the doc-load latency via resident waves)
    {
        const int qr = t >> 3;               // 0..31
        const int qc = t & 7;                // 16-float column block
        int qi = qidx[b * Q_LEN + qr];
        qi = min(max(qi, 0), V_SIZE - 1);
        const float4* src = (const float4*)(emb + (size_t)qi * E_DIM) + qc * 4;
        float4 v0 = src[0], v1 = src[1], v2 = src[2], v3 = src[3];
        float fv[16] = {v0.x,v0.y,v0.z,v0.w, v1.x,v1.y,v1.z,v1.w,
                        v2.x,v2.y,v2.z,v2.w, v3.x,v3.y,v3.z,v3.w};
        float ss = 0.f;
        half8_t h0, h1, l0, l1;
        #pragma unroll
        for (int j = 0; j < 8; ++j) {
            ss = fmaf(fv[j], fv[j], ss);
            _Float16 h = (_Float16)fv[j];
            h0[j] = h; l0[j] = (_Float16)(fv[j] - (float)h);
        }
        #pragma unroll
        for (int j = 0; j < 8; ++j) {
            ss = fmaf(fv[8 + j], fv[8 + j], ss);
            _Float16 h = (_Float16)fv[8 + j];
            h1[j] = h; l1[j] = (_Float16)(fv[8 + j] - (float)h);
        }
        const int qt  = qr >> 4;
        const int lr  = qr & 15;
        const int s   = qc >> 1;
        const int qd0 = (qc & 1) * 2;
        AfH[qt][s][qd0 * 16 + lr]       = h0;
        AfH[qt][s][(qd0 + 1) * 16 + lr] = h1;
        AfL[qt][s][qd0 * 16 + lr]       = l0;
        AfL[qt][s][(qd0 + 1) * 16 + lr] = l1;
        ss += __shfl_xor(ss, 1, 8);
        ss += __shfl_xor(ss, 2, 8);
        ss += __shfl_xor(ss, 4, 8);
        if (qc == 0) rnq[qr] = 1.0f / fmaxf(sqrtf(ss), 1e-8f);
    }
    __syncthreads();

    float rnqv[8];
    #pragma unroll
    for (int i = 0; i < 8; ++i) rnqv[i] = rnq[(i >> 2) * 16 + quad * 4 + (i & 3)];

    // ---- convert docs -> B fragments + own-column norms
    half8_t bh0[4], bl0[4], bh1[4], bl1[4];
    float rnd0, rnd1;
    {
        float ss = 0.f;
        #pragma unroll
        for (int s = 0; s < 4; ++s) {
            float f[8] = {raw0[2*s].x, raw0[2*s].y, raw0[2*s].z, raw0[2*s].w,
                          raw0[2*s+1].x, raw0[2*s+1].y, raw0[2*s+1].z, raw0[2*s+1].w};
            half8_t h, l;
            #pragma unroll
            for (int j = 0; j < 8; ++j) {
                ss = fmaf(f[j], f[j], ss);
                _Float16 hh = (_Float16)f[j];
                h[j] = hh; l[j] = (_Float16)(f[j] - (float)hh);
            }
            bh0[s] = h; bl0[s] = l;
        }
        ss += __shfl_xor(ss, 16);
        ss += __shfl_xor(ss, 32);
        rnd0 = 1.0f / fmaxf(sqrtf(ss), 1e-8f);
    }
    {
        float ss = 0.f;
        #pragma unroll
        for (int s = 0; s < 4; ++s) {
            float f[8] = {raw1[2*s].x, raw1[2*s].y, raw1[2*s].z, raw1[2*s].w,
                          raw1[2*s+1].x, raw1[2*s+1].y, raw1[2*s+1].z, raw1[2*s+1].w};
            half8_t h, l;
            #pragma unroll
            for (int j = 0; j < 8; ++j) {
                ss = fmaf(f[j], f[j], ss);
                _Float16 hh = (_Float16)f[j];
                h[j] = hh; l[j] = (_Float16)(f[j] - (float)hh);
            }
            bh1[s] = h; bl1[s] = l;
        }
        ss += __shfl_xor(ss, 16);
        ss += __shfl_xor(ss, 32);
        rnd1 = 1.0f / fmaxf(sqrtf(ss), 1e-8f);
    }

    // ---- 48 MFMAs, straight line
    float4_t acc00 = {0,0,0,0}, acc01 = {0,0,0,0};
    float4_t acc10 = {0,0,0,0}, acc11 = {0,0,0,0};
    #pragma unroll
    for (int s = 0; s < 4; ++s) {
        half8_t a0h = AfH[0][s][lane], a0l = AfL[0][s][lane];
        half8_t a1h = AfH[1][s][lane], a1l = AfL[1][s][lane];
        acc00 = __builtin_amdgcn_mfma_f32_16x16x32_f16(a0h, bh0[s], acc00, 0, 0, 0);
        acc01 = __builtin_amdgcn_mfma_f32_16x16x32_f16(a0h, bh1[s], acc01, 0, 0, 0);
        acc10 = __builtin_amdgcn_mfma_f32_16x16x32_f16(a1h, bh0[s], acc10, 0, 0, 0);
        acc11 = __builtin_amdgcn_mfma_f32_16x16x32_f16(a1h, bh1[s], acc11, 0, 0, 0);
        acc00 = __builtin_amdgcn_mfma_f32_16x16x32_f16(a0l, bh0[s], acc00, 0, 0, 0);
        acc01 = __builtin_amdgcn_mfma_f32_16x16x32_f16(a0l, bh1[s], acc01, 0, 0, 0);
        acc10 = __builtin_amdgcn_mfma_f32_16x16x32_f16(a1l, bh0[s], acc10, 0, 0, 0);
        acc11 = __builtin_amdgcn_mfma_f32_16x16x32_f16(a1l, bh1[s], acc11, 0, 0, 0);
        acc00 = __builtin_amdgcn_mfma_f32_16x16x32_f16(a0h, bl0[s], acc00, 0, 0, 0);
        acc01 = __builtin_amdgcn_mfma_f32_16x16x32_f16(a0h, bl1[s], acc01, 0, 0, 0);
        acc10 = __builtin_amdgcn_mfma_f32_16x16x32_f16(a1h, bl0[s], acc10, 0, 0, 0);
        acc11 = __builtin_amdgcn_mfma_f32_16x16x32_f16(a1h, bl1[s], acc11, 0, 0, 0);
    }

    // ---- epilogue: 16 mm -> broad reg-accum + nearest sharp bin LDS atomic
    const float cc0 = -0.5f / (0.1f * 0.1f);
    const float ccs = -0.5f / (0.001f * 0.001f);
    float breg[8] = {0.f,0.f,0.f,0.f,0.f,0.f,0.f,0.f};
    #pragma unroll
    for (int qt = 0; qt < 2; ++qt) {
        #pragma unroll
        for (int dt = 0; dt < 2; ++dt) {
            const float4_t acc = qt ? (dt ? acc11 : acc10) : (dt ? acc01 : acc00);
            const float rdv = dt ? rnd1 : rnd0;
            #pragma unroll
            for (int r = 0; r < 4; ++r) {
                const float mm = acc[r] * rnqv[qt*4 + r] * rdv;
                const float x0 = mm + 0.95f;
                breg[qt*4 + r] += __expf(x0 * x0 * cc0);
                float g = rintf((mm + 0.85f) * 10.f);
                g = fminf(fmaxf(g, 0.f), 18.f);
                float mu = fmaf(g, 0.1f, -0.85f);
                int ks = (int)g + 1;
                if (mm > 0.975f) { mu = 1.0f; ks = 20; }
                const float xs = mm - mu;
                const float es = __expf(xs * xs * ccs);
                if (es > 0.f) atomicAdd(&phis[qt*16 + quad*4 + r][ks], es);
            }
        }
    }
    #pragma unroll
    for (int i = 0; i < 8; ++i) {
        float v = breg[i];
        v += __shfl_xor(v, 1, 16);
        v += __shfl_xor(v, 2, 16);
        v += __shfl_xor(v, 4, 16);
        v += __shfl_xor(v, 8, 16);
        if (l15 == 0) atomicAdd(&phis[(i >> 2) * 16 + quad * 4 + (i & 3)][0], v);
    }
    __syncthreads();

    // ---- non-atomic flush of this block's phi partials
    const size_t gbase = (size_t)((split * 2 + pair) * B_SIZE + b) * Q_LEN * PHI_STR;
    for (int i = t; i < Q_LEN * K_NUM; i += 256) {
        const int q = i / K_NUM;
        const int k = i - q * K_NUM;
        phis_g[gbase + q * PHI_STR + k] = phis[q][k];
    }
}

__global__ __launch_bounds__(64) void knrm_reduce(
    const float* __restrict__ phis_g,
    const float* __restrict__ w1, const float* __restrict__ b1,
    const float* __restrict__ w2, const float* __restrict__ b2,
    const float* __restrict__ w3, const float* __restrict__ b3,
    float* __restrict__ out)
{
    const int b = blockIdx.x;
    const int t = threadIdx.x;               // 0..63
    const int p = t >> 5;                    // pair
    const int q = t & 31;

    const float* g0 = phis_g + ((size_t)((0 + p) * B_SIZE + b) * Q_LEN + q) * PHI_STR;
    const float* g1 = phis_g + ((size_t)((2 + p) * B_SIZE + b) * Q_LEN + q) * PHI_STR;

    float lp[K_NUM];
    #pragma unroll
    for (int k = 0; k < K_NUM; ++k) lp[k] = log1pf(g0[k] + g1[k]);
    #pragma unroll
    for (int k = 0; k < K_NUM; ++k) {
        lp[k] += __shfl_xor(lp[k], 1, 32);
        lp[k] += __shfl_xor(lp[k], 2, 32);
        lp[k] += __shfl_xor(lp[k], 4, 32);
        lp[k] += __shfl_xor(lp[k], 8, 32);
        lp[k] += __shfl_xor(lp[k], 16, 32);
    }

    float logit = 0.f;
    if (q == 0) {                            // lanes 0 and 32: per-pair MLP
        float x1v[10];
        #pragma unroll
        for (int i = 0; i < 10; ++i) {
            float s = b1[i];
            #pragma unroll
            for (int k = 0; k < K_NUM; ++k) {
                float v = lp[k] > 0.f ? lp[k] : 0.f;
                s = fmaf(v, w1[k * 10 + i], s);
            }
            x1v[i] = s;
        }
        float x2v[5];
        #pragma unroll
        for (int i = 0; i < 5; ++i) {
            float s = b2[i];
            #pragma unroll
            for (int k = 0; k < 10; ++k) {
                float v = x1v[k] > 0.f ? x1v[k] : 0.f;
                s = fmaf(v, w2[k * 5 + i], s);
            }
            x2v[i] = s;
        }
        float s3 = b3[0];
        #pragma unroll
        for (int k = 0; k < 5; ++k) {
            float v = x2v[k] > 0.f ? x2v[k] : 0.f;
            s3 = fmaf(v, w3[k], s3);
        }
        logit = s3;
    }
    const float l2 = __shfl(logit, 32);
    if (t == 0) {
        const float dl = logit - l2;
        out[b] = 1.0f / (1.0f + __expf(-dl));
    }
}

extern "C" void kernel_launch(void* const* d_in, const int* in_sizes, int n_in,
                              void* d_out, int out_size, void* d_ws, size_t ws_size,
                              hipStream_t stream)
{
    const float* emb = (const float*)d_in[0];
    const float* w1  = (const float*)d_in[1];
    const float* b1  = (const float*)d_in[2];
    const float* w2  = (const float*)d_in[3];
    const float* b2  = (const float*)d_in[4];
    const float* w3  = (const float*)d_in[5];
    const float* b3  = (const float*)d_in[6];
    const int*   q1  = (const int*)d_in[7];
    const int*   d1  = (const int*)d_in[8];
    const int*   q2  = (const int*)d_in[9];
    const int*   d2  = (const int*)d_in[10];

    float* phis_g = (float*)d_ws;            // [4][B][32][24] = 3.1 MB
    float* out    = (float*)d_out;

    dim3 grid(B_SIZE, 2, 2);
    knrm_gemm<<<grid, 256, 0, stream>>>(emb, q1, d1, q2, d2, phis_g);
    knrm_reduce<<<B_SIZE, 64, 0, stream>>>(phis_g, w1, b1, w2, b2, w3, b3, out);
}

// Round 7
// 174.953 us; speedup vs baseline: 1.1990x; 1.1990x over previous
//
#include <hip/hip_runtime.h>
#include <math.h>

#define V_SIZE  100000
#define E_DIM   128
#define B_SIZE  512
#define Q_LEN   32
#define D_LEN   256
#define K_NUM   21
#define PHI_STR 24    // padded k-stride in the global phi buffer

// Kernel params (faithful to the reference's swapped sigma call):
// mus ascending: [-0.95, -0.85, ..., 0.85, 0.95, 1.0]
// sigmas descending: [0.1, 0.001 x 20]  -> k=0 broad (mu=-0.95), k>=1 sharp.
//
// Nearest-bin exactness: sharp sigma=1e-3 -> exp underflows to 0.0f once
// |mm-mu| > 0.01443; sharp mus are >=0.05 apart -> at most ONE sharp bin
// nonzero per mm. broad + nearest-sharp == all 21 bins (R2-R6: absmax 0).
//
// fp16-split matmul: a = hi + lo (both fp16); hi*hi + lo*hi + hi*lo drops only
// lo*lo (<=2^-22|a||b|) -> mm error ~1e-6 (R3-R6: absmax 0).
//
// R7: R5 structure with __launch_bounds__(256, 6).
//   (256,4): VGPR 60, no spill, occ 31%  -> latency-bound (R5, 43 us)
//   (256,8): 64-reg budget -> VGPR 32 + 172MB scratch spill -> 112+ us (R6)
//   (256,6): 80-reg budget holds the ~60-reg live set, 24 waves/CU.
// LDS 19456 x 6 = 114KB <= 160KB -> LDS not binding.

typedef _Float16 half8_t  __attribute__((ext_vector_type(8)));
typedef float    float4_t __attribute__((ext_vector_type(4)));

__global__ __launch_bounds__(256, 6) void knrm_gemm(
    const float* __restrict__ emb,
    const int* __restrict__ q1, const int* __restrict__ d1,
    const int* __restrict__ q2, const int* __restrict__ d2,
    float* __restrict__ phis_g)
{
    const int b     = blockIdx.x;
    const int pair  = blockIdx.y;
    const int split = blockIdx.z;
    const int t     = threadIdx.x;           // 0..255
    const int* __restrict__ qidx = pair ? q2 : q1;
    const int* __restrict__ didx = pair ? d2 : d1;

    __shared__ half8_t AfH[2][4][64];        // [qt][s][lane] query hi fragments
    __shared__ half8_t AfL[2][4][64];        // lo fragments
    __shared__ float rnq[Q_LEN];
    __shared__ float phis[Q_LEN][22];

    const int lane = t & 63;
    const int w    = t >> 6;                 // wave 0..3
    const int quad = lane >> 4;
    const int l15  = lane & 15;

    for (int i = t; i < Q_LEN * 22; i += 256) ((float*)phis)[i] = 0.f;

    // ---- doc gathers: wave owns docs dbase..dbase+31 (two 16x16 B tiles)
    const int dbase = split * 128 + w * 32;
    int di0 = didx[b * D_LEN + dbase + l15];
    int di1 = didx[b * D_LEN + dbase + 16 + l15];
    di0 = min(max(di0, 0), V_SIZE - 1);
    di1 = min(max(di1, 0), V_SIZE - 1);
    const float4* dr0 = (const float4*)(emb + (size_t)di0 * E_DIM) + quad * 2;
    const float4* dr1 = (const float4*)(emb + (size_t)di1 * E_DIM) + quad * 2;
    float4 raw0[8], raw1[8];
    #pragma unroll
    for (int s = 0; s < 4; ++s) {
        raw0[2*s]   = dr0[s*8];
        raw0[2*s+1] = dr0[s*8+1];
        raw1[2*s]   = dr1[s*8];
        raw1[2*s+1] = dr1[s*8+1];
    }

    // ---- query phase (overlaps the doc-load latency via resident waves)
    {
        const int qr = t >> 3;               // 0..31
        const int qc = t & 7;                // 16-float column block
        int qi = qidx[b * Q_LEN + qr];
        qi = min(max(qi, 0), V_SIZE - 1);
        const float4* src = (const float4*)(emb + (size_t)qi * E_DIM) + qc * 4;
        float4 v0 = src[0], v1 = src[1], v2 = src[2], v3 = src[3];
        float fv[16] = {v0.x,v0.y,v0.z,v0.w, v1.x,v1.y,v1.z,v1.w,
                        v2.x,v2.y,v2.z,v2.w, v3.x,v3.y,v3.z,v3.w};
        float ss = 0.f;
        half8_t h0, h1, l0, l1;
        #pragma unroll
        for (int j = 0; j < 8; ++j) {
            ss = fmaf(fv[j], fv[j], ss);
            _Float16 h = (_Float16)fv[j];
            h0[j] = h; l0[j] = (_Float16)(fv[j] - (float)h);
        }
        #pragma unroll
        for (int j = 0; j < 8; ++j) {
            ss = fmaf(fv[8 + j], fv[8 + j], ss);
            _Float16 h = (_Float16)fv[8 + j];
            h1[j] = h; l1[j] = (_Float16)(fv[8 + j] - (float)h);
        }
        const int qt  = qr >> 4;
        const int lr  = qr & 15;
        const int s   = qc >> 1;
        const int qd0 = (qc & 1) * 2;
        AfH[qt][s][qd0 * 16 + lr]       = h0;
        AfH[qt][s][(qd0 + 1) * 16 + lr] = h1;
        AfL[qt][s][qd0 * 16 + lr]       = l0;
        AfL[qt][s][(qd0 + 1) * 16 + lr] = l1;
        ss += __shfl_xor(ss, 1, 8);
        ss += __shfl_xor(ss, 2, 8);
        ss += __shfl_xor(ss, 4, 8);
        if (qc == 0) rnq[qr] = 1.0f / fmaxf(sqrtf(ss), 1e-8f);
    }
    __syncthreads();

    float rnqv[8];
    #pragma unroll
    for (int i = 0; i < 8; ++i) rnqv[i] = rnq[(i >> 2) * 16 + quad * 4 + (i & 3)];

    // ---- convert docs -> B fragments + own-column norms
    half8_t bh0[4], bl0[4], bh1[4], bl1[4];
    float rnd0, rnd1;
    {
        float ss = 0.f;
        #pragma unroll
        for (int s = 0; s < 4; ++s) {
            float f[8] = {raw0[2*s].x, raw0[2*s].y, raw0[2*s].z, raw0[2*s].w,
                          raw0[2*s+1].x, raw0[2*s+1].y, raw0[2*s+1].z, raw0[2*s+1].w};
            half8_t h, l;
            #pragma unroll
            for (int j = 0; j < 8; ++j) {
                ss = fmaf(f[j], f[j], ss);
                _Float16 hh = (_Float16)f[j];
                h[j] = hh; l[j] = (_Float16)(f[j] - (float)hh);
            }
            bh0[s] = h; bl0[s] = l;
        }
        ss += __shfl_xor(ss, 16);
        ss += __shfl_xor(ss, 32);
        rnd0 = 1.0f / fmaxf(sqrtf(ss), 1e-8f);
    }
    {
        float ss = 0.f;
        #pragma unroll
        for (int s = 0; s < 4; ++s) {
            float f[8] = {raw1[2*s].x, raw1[2*s].y, raw1[2*s].z, raw1[2*s].w,
                          raw1[2*s+1].x, raw1[2*s+1].y, raw1[2*s+1].z, raw1[2*s+1].w};
            half8_t h, l;
            #pragma unroll
            for (int j = 0; j < 8; ++j) {
                ss = fmaf(f[j], f[j], ss);
                _Float16 hh = (_Float16)f[j];
                h[j] = hh; l[j] = (_Float16)(f[j] - (float)hh);
            }
            bh1[s] = h; bl1[s] = l;
        }
        ss += __shfl_xor(ss, 16);
        ss += __shfl_xor(ss, 32);
        rnd1 = 1.0f / fmaxf(sqrtf(ss), 1e-8f);
    }

    // ---- 48 MFMAs, straight line
    float4_t acc00 = {0,0,0,0}, acc01 = {0,0,0,0};
    float4_t acc10 = {0,0,0,0}, acc11 = {0,0,0,0};
    #pragma unroll
    for (int s = 0; s < 4; ++s) {
        half8_t a0h = AfH[0][s][lane], a0l = AfL[0][s][lane];
        half8_t a1h = AfH[1][s][lane], a1l = AfL[1][s][lane];
        acc00 = __builtin_amdgcn_mfma_f32_16x16x32_f16(a0h, bh0[s], acc00, 0, 0, 0);
        acc01 = __builtin_amdgcn_mfma_f32_16x16x32_f16(a0h, bh1[s], acc01, 0, 0, 0);
        acc10 = __builtin_amdgcn_mfma_f32_16x16x32_f16(a1h, bh0[s], acc10, 0, 0, 0);
        acc11 = __builtin_amdgcn_mfma_f32_16x16x32_f16(a1h, bh1[s], acc11, 0, 0, 0);
        acc00 = __builtin_amdgcn_mfma_f32_16x16x32_f16(a0l, bh0[s], acc00, 0, 0, 0);
        acc01 = __builtin_amdgcn_mfma_f32_16x16x32_f16(a0l, bh1[s], acc01, 0, 0, 0);
        acc10 = __builtin_amdgcn_mfma_f32_16x16x32_f16(a1l, bh0[s], acc10, 0, 0, 0);
        acc11 = __builtin_amdgcn_mfma_f32_16x16x32_f16(a1l, bh1[s], acc11, 0, 0, 0);
        acc00 = __builtin_amdgcn_mfma_f32_16x16x32_f16(a0h, bl0[s], acc00, 0, 0, 0);
        acc01 = __builtin_amdgcn_mfma_f32_16x16x32_f16(a0h, bl1[s], acc01, 0, 0, 0);
        acc10 = __builtin_amdgcn_mfma_f32_16x16x32_f16(a1h, bl0[s], acc10, 0, 0, 0);
        acc11 = __builtin_amdgcn_mfma_f32_16x16x32_f16(a1h, bl1[s], acc11, 0, 0, 0);
    }

    // ---- epilogue: 16 mm -> broad reg-accum + nearest sharp bin LDS atomic
    const float cc0 = -0.5f / (0.1f * 0.1f);
    const float ccs = -0.5f / (0.001f * 0.001f);
    float breg[8] = {0.f,0.f,0.f,0.f,0.f,0.f,0.f,0.f};
    #pragma unroll
    for (int qt = 0; qt < 2; ++qt) {
        #pragma unroll
        for (int dt = 0; dt < 2; ++dt) {
            const float4_t acc = qt ? (dt ? acc11 : acc10) : (dt ? acc01 : acc00);
            const float rdv = dt ? rnd1 : rnd0;
            #pragma unroll
            for (int r = 0; r < 4; ++r) {
                const float mm = acc[r] * rnqv[qt*4 + r] * rdv;
                const float x0 = mm + 0.95f;
                breg[qt*4 + r] += __expf(x0 * x0 * cc0);
                float g = rintf((mm + 0.85f) * 10.f);
                g = fminf(fmaxf(g, 0.f), 18.f);
                float mu = fmaf(g, 0.1f, -0.85f);
                int ks = (int)g + 1;
                if (mm > 0.975f) { mu = 1.0f; ks = 20; }
                const float xs = mm - mu;
                const float es = __expf(xs * xs * ccs);
                if (es > 0.f) atomicAdd(&phis[qt*16 + quad*4 + r][ks], es);
            }
        }
    }
    #pragma unroll
    for (int i = 0; i < 8; ++i) {
        float v = breg[i];
        v += __shfl_xor(v, 1, 16);
        v += __shfl_xor(v, 2, 16);
        v += __shfl_xor(v, 4, 16);
        v += __shfl_xor(v, 8, 16);
        if (l15 == 0) atomicAdd(&phis[(i >> 2) * 16 + quad * 4 + (i & 3)][0], v);
    }
    __syncthreads();

    // ---- non-atomic flush of this block's phi partials
    const size_t gbase = (size_t)((split * 2 + pair) * B_SIZE + b) * Q_LEN * PHI_STR;
    for (int i = t; i < Q_LEN * K_NUM; i += 256) {
        const int q = i / K_NUM;
        const int k = i - q * K_NUM;
        phis_g[gbase + q * PHI_STR + k] = phis[q][k];
    }
}

__global__ __launch_bounds__(64) void knrm_reduce(
    const float* __restrict__ phis_g,
    const float* __restrict__ w1, const float* __restrict__ b1,
    const float* __restrict__ w2, const float* __restrict__ b2,
    const float* __restrict__ w3, const float* __restrict__ b3,
    float* __restrict__ out)
{
    const int b = blockIdx.x;
    const int t = threadIdx.x;               // 0..63
    const int p = t >> 5;                    // pair
    const int q = t & 31;

    const float* g0 = phis_g + ((size_t)((0 + p) * B_SIZE + b) * Q_LEN + q) * PHI_STR;
    const float* g1 = phis_g + ((size_t)((2 + p) * B_SIZE + b) * Q_LEN + q) * PHI_STR;

    float lp[K_NUM];
    #pragma unroll
    for (int k = 0; k < K_NUM; ++k) lp[k] = log1pf(g0[k] + g1[k]);
    #pragma unroll
    for (int k = 0; k < K_NUM; ++k) {
        lp[k] += __shfl_xor(lp[k], 1, 32);
        lp[k] += __shfl_xor(lp[k], 2, 32);
        lp[k] += __shfl_xor(lp[k], 4, 32);
        lp[k] += __shfl_xor(lp[k], 8, 32);
        lp[k] += __shfl_xor(lp[k], 16, 32);
    }

    float logit = 0.f;
    if (q == 0) {                            // lanes 0 and 32: per-pair MLP
        float x1v[10];
        #pragma unroll
        for (int i = 0; i < 10; ++i) {
            float s = b1[i];
            #pragma unroll
            for (int k = 0; k < K_NUM; ++k) {
                float v = lp[k] > 0.f ? lp[k] : 0.f;
                s = fmaf(v, w1[k * 10 + i], s);
            }
            x1v[i] = s;
        }
        float x2v[5];
        #pragma unroll
        for (int i = 0; i < 5; ++i) {
            float s = b2[i];
            #pragma unroll
            for (int k = 0; k < 10; ++k) {
                float v = x1v[k] > 0.f ? x1v[k] : 0.f;
                s = fmaf(v, w2[k * 5 + i], s);
            }
            x2v[i] = s;
        }
        float s3 = b3[0];
        #pragma unroll
        for (int k = 0; k < 5; ++k) {
            float v = x2v[k] > 0.f ? x2v[k] : 0.f;
            s3 = fmaf(v, w3[k], s3);
        }
        logit = s3;
    }
    const float l2 = __shfl(logit, 32);
    if (t == 0) {
        const float dl = logit - l2;
        out[b] = 1.0f / (1.0f + __expf(-dl));
    }
}

extern "C" void kernel_launch(void* const* d_in, const int* in_sizes, int n_in,
                              void* d_out, int out_size, void* d_ws, size_t ws_size,
                              hipStream_t stream)
{
    const float* emb = (const float*)d_in[0];
    const float* w1  = (const float*)d_in[1];
    const float* b1  = (const float*)d_in[2];
    const float* w2  = (const float*)d_in[3];
    const float* b2  = (const float*)d_in[4];
    const float* w3  = (const float*)d_in[5];
    const float* b3  = (const float*)d_in[6];
    const int*   q1  = (const int*)d_in[7];
    const int*   d1  = (const int*)d_in[8];
    const int*   q2  = (const int*)d_in[9];
    const int*   d2  = (const int*)d_in[10];

    float* phis_g = (float*)d_ws;            // [4][B][32][24] = 3.1 MB
    float* out    = (float*)d_out;

    dim3 grid(B_SIZE, 2, 2);
    knrm_gemm<<<grid, 256, 0, stream>>>(emb, q1, d1, q2, d2, phis_g);
    knrm_reduce<<<B_SIZE, 64, 0, stream>>>(phis_g, w1, b1, w2, b2, w3, b3, out);
}

// Round 8
// 136.060 us; speedup vs baseline: 1.5417x; 1.2859x over previous
//
#include <hip/hip_runtime.h>
#include <math.h>

#define V_SIZE  100000
#define E_DIM   128
#define B_SIZE  512
#define Q_LEN   32
#define D_LEN   256
#define K_NUM   21

// Kernel params (faithful to the reference's swapped sigma call):
// mus ascending: [-0.95, -0.85, ..., 0.85, 0.95, 1.0]
// sigmas descending: [0.1, 0.001 x 20]  -> k=0 broad (mu=-0.95), k>=1 sharp.
//
// Nearest-bin exactness: sharp sigma=1e-3 -> exp underflows to 0.0f once
// |mm-mu| > 0.01443; sharp mus are >=0.05 apart -> at most ONE sharp bin
// nonzero per mm. broad + nearest-sharp == all 21 bins (R2-R7: absmax 0).
//
// fp16-split matmul: a = hi + lo (both fp16); hi*hi + lo*hi + hi*lo drops only
// lo*lo (<=2^-22|a||b|) -> mm error ~1e-6 (R3-R7: absmax 0).
//
// R8: doc gathers via global_load_lds (direct-to-LDS DMA). R5-R7 showed the
// register file cannot be both the latency buffer and the compute workspace
// (sunk loads at (256,4); 110-172MB scratch spills at (256,6/8)). The DMA
// path holds in-flight data in the vmcnt queue instead: zero VGPRs.
// Staging layout is FRAG-LINEAR: inst (s,h) -> LDS base (s*2+h)*1024,
// lane i slot = +i*16 holds doc(i&15) floats [s*32+(i>>4)*8+h*4, +4).
// Convert = 8 lane-linear ds_read_b128 (conflict-free), no transpose.
// Per-wave chunk loop, no barriers: wait vmcnt(0) -> convert -> reissue
// buffer for c+1 -> 24 MFMA + epilogue under the next chunk's flight.
// LDS 32K stage + 16K A-frags + phis ~ 51KB -> 3 blocks/CU = 12 waves/CU.

typedef _Float16 half8_t  __attribute__((ext_vector_type(8)));
typedef float    float4_t __attribute__((ext_vector_type(4)));

#define GLOBAL_AS __attribute__((address_space(1)))
#define LDS_AS    __attribute__((address_space(3)))

__global__ __launch_bounds__(256, 3) void knrm_gemm(
    const float* __restrict__ emb,
    const int* __restrict__ q1, const int* __restrict__ d1,
    const int* __restrict__ q2, const int* __restrict__ d2,
    float* __restrict__ logits)
{
    const int b    = blockIdx.x;
    const int pair = blockIdx.y;
    const int t    = threadIdx.x;            // 0..255
    const int* __restrict__ qidx = pair ? q2 : q1;
    const int* __restrict__ didx = pair ? d2 : d1;

    __shared__ __align__(16) unsigned char stage[4][8192];  // [wave][16-doc chunk]
    __shared__ half8_t AfH[2][4][64];        // [qt][s][lane] query hi fragments
    __shared__ half8_t AfL[2][4][64];        // lo fragments
    __shared__ float rnq[Q_LEN];
    __shared__ float phis[Q_LEN][22];
    __shared__ float ko[K_NUM];

    const int lane = t & 63;
    const int w    = t >> 6;                 // wave 0..3 -> docs w*64..+63
    const int quad = lane >> 4;
    const int l15  = lane & 15;

    for (int i = t; i < Q_LEN * 22; i += 256) ((float*)phis)[i] = 0.f;

    // ---- doc row bases: chunk c docs = w*64 + c*16 + l15 (lane's own doc)
    const unsigned char* grow[4];
    #pragma unroll
    for (int c = 0; c < 4; ++c) {
        int di = didx[b * D_LEN + w * 64 + c * 16 + l15];
        di = min(max(di, 0), V_SIZE - 1);
        grow[c] = (const unsigned char*)(emb + (size_t)di * E_DIM) + quad * 32;
    }

    // ---- issue chunk-0 DMA (latency hides under the query phase)
    #pragma unroll
    for (int s = 0; s < 4; ++s) {
        #pragma unroll
        for (int h = 0; h < 2; ++h) {
            __builtin_amdgcn_global_load_lds(
                (const GLOBAL_AS void*)(grow[0] + s * 128 + h * 16),
                (LDS_AS void*)(&stage[w][(s * 2 + h) * 1024]), 16, 0, 0);
        }
    }

    // ---- query phase: rows -> fp16 hi/lo fragments in LDS + rnq
    {
        const int qr = t >> 3;               // 0..31
        const int qc = t & 7;                // 16-float column block
        int qi = qidx[b * Q_LEN + qr];
        qi = min(max(qi, 0), V_SIZE - 1);
        const float4* src = (const float4*)(emb + (size_t)qi * E_DIM) + qc * 4;
        float4 v0 = src[0], v1 = src[1], v2 = src[2], v3 = src[3];
        float fv[16] = {v0.x,v0.y,v0.z,v0.w, v1.x,v1.y,v1.z,v1.w,
                        v2.x,v2.y,v2.z,v2.w, v3.x,v3.y,v3.z,v3.w};
        float ss = 0.f;
        half8_t h0, h1, l0, l1;
        #pragma unroll
        for (int j = 0; j < 8; ++j) {
            ss = fmaf(fv[j], fv[j], ss);
            _Float16 h = (_Float16)fv[j];
            h0[j] = h; l0[j] = (_Float16)(fv[j] - (float)h);
        }
        #pragma unroll
        for (int j = 0; j < 8; ++j) {
            ss = fmaf(fv[8 + j], fv[8 + j], ss);
            _Float16 h = (_Float16)fv[8 + j];
            h1[j] = h; l1[j] = (_Float16)(fv[8 + j] - (float)h);
        }
        const int qt  = qr >> 4;
        const int lr  = qr & 15;
        const int s   = qc >> 1;
        const int qd0 = (qc & 1) * 2;
        AfH[qt][s][qd0 * 16 + lr]       = h0;
        AfH[qt][s][(qd0 + 1) * 16 + lr] = h1;
        AfL[qt][s][qd0 * 16 + lr]       = l0;
        AfL[qt][s][(qd0 + 1) * 16 + lr] = l1;
        ss += __shfl_xor(ss, 1, 8);
        ss += __shfl_xor(ss, 2, 8);
        ss += __shfl_xor(ss, 4, 8);
        if (qc == 0) rnq[qr] = 1.0f / fmaxf(sqrtf(ss), 1e-8f);
    }
    __syncthreads();

    float rnqv[8];
    #pragma unroll
    for (int i = 0; i < 8; ++i) rnqv[i] = rnq[(i >> 2) * 16 + quad * 4 + (i & 3)];

    const float cc0 = -0.5f / (0.1f * 0.1f);
    const float ccs = -0.5f / (0.001f * 0.001f);
    float breg[8] = {0.f,0.f,0.f,0.f,0.f,0.f,0.f,0.f};

    // ---- per-wave chunk loop: 4 chunks of 16 docs, no barriers
    #pragma unroll 1
    for (int c = 0; c < 4; ++c) {
        asm volatile("s_waitcnt vmcnt(0)" ::: "memory");   // chunk c staged

        // convert: 8 lane-linear ds_read_b128 -> B frags + own-doc norm
        half8_t bh[4], bl[4];
        float ss = 0.f;
        #pragma unroll
        for (int s = 0; s < 4; ++s) {
            float4 v0 = *(const float4*)&stage[w][(s * 2 + 0) * 1024 + lane * 16];
            float4 v1 = *(const float4*)&stage[w][(s * 2 + 1) * 1024 + lane * 16];
            float f[8] = {v0.x,v0.y,v0.z,v0.w, v1.x,v1.y,v1.z,v1.w};
            half8_t h, l;
            #pragma unroll
            for (int j = 0; j < 8; ++j) {
                ss = fmaf(f[j], f[j], ss);
                _Float16 hh = (_Float16)f[j];
                h[j] = hh; l[j] = (_Float16)(f[j] - (float)hh);
            }
            bh[s] = h; bl[s] = l;
        }
        ss += __shfl_xor(ss, 16);
        ss += __shfl_xor(ss, 32);
        const float rnd = 1.0f / fmaxf(sqrtf(ss), 1e-8f);

        // buffer free (frags in regs) -> issue chunk c+1 DMA
        asm volatile("s_waitcnt lgkmcnt(0)" ::: "memory"); // ds_reads drained
        if (c < 3) {
            #pragma unroll
            for (int s = 0; s < 4; ++s) {
                #pragma unroll
                for (int h = 0; h < 2; ++h) {
                    __builtin_amdgcn_global_load_lds(
                        (const GLOBAL_AS void*)(grow[c + 1] + s * 128 + h * 16),
                        (LDS_AS void*)(&stage[w][(s * 2 + h) * 1024]), 16, 0, 0);
                }
            }
        }

        // 24 MFMAs (2 q-tiles x 4 s x hi/lo split) under the next chunk's flight
        float4_t acc0 = {0,0,0,0}, acc1 = {0,0,0,0};
        #pragma unroll
        for (int s = 0; s < 4; ++s) {
            half8_t a0h = AfH[0][s][lane], a0l = AfL[0][s][lane];
            half8_t a1h = AfH[1][s][lane], a1l = AfL[1][s][lane];
            acc0 = __builtin_amdgcn_mfma_f32_16x16x32_f16(a0h, bh[s], acc0, 0, 0, 0);
            acc1 = __builtin_amdgcn_mfma_f32_16x16x32_f16(a1h, bh[s], acc1, 0, 0, 0);
            acc0 = __builtin_amdgcn_mfma_f32_16x16x32_f16(a0l, bh[s], acc0, 0, 0, 0);
            acc1 = __builtin_amdgcn_mfma_f32_16x16x32_f16(a1l, bh[s], acc1, 0, 0, 0);
            acc0 = __builtin_amdgcn_mfma_f32_16x16x32_f16(a0h, bl[s], acc0, 0, 0, 0);
            acc1 = __builtin_amdgcn_mfma_f32_16x16x32_f16(a1h, bl[s], acc1, 0, 0, 0);
        }

        // epilogue: 8 mm -> broad reg-accum + nearest sharp bin LDS atomic
        #pragma unroll
        for (int qt = 0; qt < 2; ++qt) {
            const float4_t acc = qt ? acc1 : acc0;
            #pragma unroll
            for (int r = 0; r < 4; ++r) {
                const float mm = acc[r] * rnqv[qt * 4 + r] * rnd;
                const float x0 = mm + 0.95f;
                breg[qt * 4 + r] += __expf(x0 * x0 * cc0);
                float g = rintf((mm + 0.85f) * 10.f);
                g = fminf(fmaxf(g, 0.f), 18.f);
                float mu = fmaf(g, 0.1f, -0.85f);
                int ks = (int)g + 1;
                if (mm > 0.975f) { mu = 1.0f; ks = 20; }
                const float xs = mm - mu;
                const float es = __expf(xs * xs * ccs);
                if (es > 0.f) atomicAdd(&phis[qt * 16 + quad * 4 + r][ks], es);
            }
        }
    }

    // ---- broad-bin: reduce across the 16 lanes sharing each q
    #pragma unroll
    for (int i = 0; i < 8; ++i) {
        float v = breg[i];
        v += __shfl_xor(v, 1, 16);
        v += __shfl_xor(v, 2, 16);
        v += __shfl_xor(v, 4, 16);
        v += __shfl_xor(v, 8, 16);
        if (l15 == 0) atomicAdd(&phis[(i >> 2) * 16 + quad * 4 + (i & 3)][0], v);
    }
    __syncthreads();

    // ---- ko[k] = sum_q log1p(phis[q][k])
    for (int p = t; p < K_NUM * Q_LEN; p += 256) {
        const int q = p & 31;
        const int k = p >> 5;
        float l = log1pf(phis[q][k]);
        l += __shfl_xor(l, 1, 32);
        l += __shfl_xor(l, 2, 32);
        l += __shfl_xor(l, 4, 32);
        l += __shfl_xor(l, 8, 32);
        l += __shfl_xor(l, 16, 32);
        if (q == 0) ko[k] = l;
    }
    __syncthreads();

    // ---- MLP 21 -> 10 -> 5 -> 1 (thread 0); weights read in reduce kernel?
    if (t == 0) {
        // store k_out; MLP done in the tiny final kernel to keep this one lean
        // (we inline it here instead: logits slot per (pair,b))
        // NOTE: weights are fetched by the final kernel; here we just flush ko.
    }
    // flush ko to logits buffer region: [pair][b][K_NUM] handled by final kernel
    if (t < K_NUM) {
        logits[((size_t)pair * B_SIZE + b) * K_NUM + t] = ko[t];
    }
}

__global__ __launch_bounds__(64) void knrm_final(
    const float* __restrict__ kout,
    const float* __restrict__ w1, const float* __restrict__ b1,
    const float* __restrict__ w2, const float* __restrict__ b2,
    const float* __restrict__ w3, const float* __restrict__ b3,
    float* __restrict__ out)
{
    const int b = blockIdx.x * 32 + (threadIdx.x & 31);
    const int p = threadIdx.x >> 5;          // pair handled per half-wave? no:
    // each thread computes BOTH pairs' MLP for one b (cheap, 2x ~300 flops)
    if (threadIdx.x >= 32) return;
    if (b >= B_SIZE) return;

    float logit[2];
    #pragma unroll
    for (int pr = 0; pr < 2; ++pr) {
        const float* ko = kout + ((size_t)pr * B_SIZE + b) * K_NUM;
        float x1v[10];
        #pragma unroll
        for (int i = 0; i < 10; ++i) {
            float s = b1[i];
            #pragma unroll
            for (int k = 0; k < K_NUM; ++k) {
                float v = ko[k] > 0.f ? ko[k] : 0.f;
                s = fmaf(v, w1[k * 10 + i], s);
            }
            x1v[i] = s;
        }
        float x2v[5];
        #pragma unroll
        for (int i = 0; i < 5; ++i) {
            float s = b2[i];
            #pragma unroll
            for (int k = 0; k < 10; ++k) {
                float v = x1v[k] > 0.f ? x1v[k] : 0.f;
                s = fmaf(v, w2[k * 5 + i], s);
            }
            x2v[i] = s;
        }
        float s3 = b3[0];
        #pragma unroll
        for (int k = 0; k < 5; ++k) {
            float v = x2v[k] > 0.f ? x2v[k] : 0.f;
            s3 = fmaf(v, w3[k], s3);
        }
        logit[pr] = s3;
    }
    const float dl = logit[0] - logit[1];
    out[b] = 1.0f / (1.0f + __expf(-dl));
}

extern "C" void kernel_launch(void* const* d_in, const int* in_sizes, int n_in,
                              void* d_out, int out_size, void* d_ws, size_t ws_size,
                              hipStream_t stream)
{
    const float* emb = (const float*)d_in[0];
    const float* w1  = (const float*)d_in[1];
    const float* b1  = (const float*)d_in[2];
    const float* w2  = (const float*)d_in[3];
    const float* b2  = (const float*)d_in[4];
    const float* w3  = (const float*)d_in[5];
    const float* b3  = (const float*)d_in[6];
    const int*   q1  = (const int*)d_in[7];
    const int*   d1  = (const int*)d_in[8];
    const int*   q2  = (const int*)d_in[9];
    const int*   d2  = (const int*)d_in[10];

    float* kout = (float*)d_ws;              // [2][B_SIZE][K_NUM]
    float* out  = (float*)d_out;

    dim3 grid(B_SIZE, 2);
    knrm_gemm<<<grid, 256, 0, stream>>>(emb, q1, d1, q2, d2, kout);
    knrm_final<<<(B_SIZE + 31) / 32, 64, 0, stream>>>(kout, w1, b1, w2, b2, w3, b3, out);
}

// Round 9
// 129.245 us; speedup vs baseline: 1.6230x; 1.0527x over previous
//
#include <hip/hip_runtime.h>
#include <math.h>

#define V_SIZE 100000
#define E_DIM  128
#define B_SIZE 512
#define Q_LEN  32
#define D_LEN  256
#define K_NUM  21

// Kernel params (faithful to the reference's swapped sigma call):
// mus ascending: [-0.95, -0.85, ..., 0.85, 0.95, 1.0]
// sigmas descending: [0.1, 0.001 x 20]  -> k=0 broad (mu=-0.95), k>=1 sharp.
//
// Nearest-bin exactness: sharp sigma=1e-3 -> exp underflows to 0.0f once
// |mm-mu| > 0.01443; sharp mus are >=0.05 apart -> at most ONE sharp bin
// nonzero per mm. broad + nearest-sharp == all 21 bins (R2-R8: absmax 0).
//
// fp16-split matmul: a = hi + lo (both fp16). hi*hi + lo*hi + hi*lo drops only
// lo*lo (<=2^-22|a||b|) -> mm error ~1e-6, fp32-class (R3-R8: absmax 0).
//
// R9 = R4 (best measured total, 124.7us) with __launch_bounds__(256, 5).
// Session ladder on occupancy/spill:
//   (256,4): VGPR 52, no spill, 16 waves/CU -> best structure (R4)
//   (256,8): budget 64 -> 172MB scratch spill (R6);  (256,6): 110MB spill (R7)
//   (256,5): budget ~96 holds the ~52-reg sunk-load live set; LDS 19456x5=95KB
//            -> 5 blocks/CU, 20 waves/CU. Spill tripwire: WRITE_SIZE.

typedef _Float16 half8_t  __attribute__((ext_vector_type(8)));
typedef float    float4_t __attribute__((ext_vector_type(4)));

__global__ __launch_bounds__(256, 5) void knrm_main(
    const float* __restrict__ emb,
    const int* __restrict__ q1, const int* __restrict__ d1,
    const int* __restrict__ q2, const int* __restrict__ d2,
    const float* __restrict__ w1, const float* __restrict__ b1,
    const float* __restrict__ w2, const float* __restrict__ b2,
    const float* __restrict__ w3, const float* __restrict__ b3,
    float* __restrict__ logits)
{
    const int b    = blockIdx.x;
    const int pair = blockIdx.y;
    const int t    = threadIdx.x;            // 0..255
    const int* __restrict__ qidx = pair ? q2 : q1;
    const int* __restrict__ didx = pair ? d2 : d1;

    __shared__ half8_t AfH[2][4][64];        // [qt][s][lane] query hi fragments
    __shared__ half8_t AfL[2][4][64];        // lo fragments
    __shared__ float rnq[Q_LEN];
    __shared__ float phis[Q_LEN][22];        // k = 0..20
    __shared__ float ko[K_NUM];

    const int lane = t & 63;
    const int w    = t >> 6;                 // wave 0..3 -> owns docs w*64..+63
    const int quad = lane >> 4;
    const int l15  = lane & 15;

    // ---- phis init
    for (int i = t; i < Q_LEN * 22; i += 256) ((float*)phis)[i] = 0.f;

    // ---- Phase 1: queries -> fp16 hi/lo fragments in LDS (+ rnq)
    {
        const int qr = t >> 3;               // 0..31
        const int qc = t & 7;                // 16-float column block
        int qi = qidx[b * Q_LEN + qr];
        qi = min(max(qi, 0), V_SIZE - 1);
        const float4* src = (const float4*)(emb + (size_t)qi * E_DIM) + qc * 4;
        float4 v0 = src[0], v1 = src[1], v2 = src[2], v3 = src[3];
        float fv[16] = {v0.x,v0.y,v0.z,v0.w, v1.x,v1.y,v1.z,v1.w,
                        v2.x,v2.y,v2.z,v2.w, v3.x,v3.y,v3.z,v3.w};
        float ss = 0.f;
        half8_t h0, h1, l0, l1;
        #pragma unroll
        for (int j = 0; j < 8; ++j) {
            ss = fmaf(fv[j], fv[j], ss);
            _Float16 h = (_Float16)fv[j];
            h0[j] = h; l0[j] = (_Float16)(fv[j] - (float)h);
        }
        #pragma unroll
        for (int j = 0; j < 8; ++j) {
            ss = fmaf(fv[8 + j], fv[8 + j], ss);
            _Float16 h = (_Float16)fv[8 + j];
            h1[j] = h; l1[j] = (_Float16)(fv[8 + j] - (float)h);
        }
        // fragment-order store: k-base qc*16 -> s = qc>>1, quad = (qc&1)*2 (+1)
        const int qt  = qr >> 4;
        const int lr  = qr & 15;
        const int s   = qc >> 1;
        const int qd0 = (qc & 1) * 2;
        AfH[qt][s][qd0 * 16 + lr]       = h0;
        AfH[qt][s][(qd0 + 1) * 16 + lr] = h1;
        AfL[qt][s][qd0 * 16 + lr]       = l0;
        AfL[qt][s][(qd0 + 1) * 16 + lr] = l1;
        ss += __shfl_xor(ss, 1, 8);
        ss += __shfl_xor(ss, 2, 8);
        ss += __shfl_xor(ss, 4, 8);
        if (qc == 0) rnq[qr] = 1.0f / fmaxf(sqrtf(ss), 1e-8f);
    }
    __syncthreads();

    float rnqv[8];
    #pragma unroll
    for (int i = 0; i < 8; ++i) rnqv[i] = rnq[(i >> 2) * 16 + quad * 4 + (i & 3)];

    const float cc0 = -0.5f / (0.1f * 0.1f);
    const float ccs = -0.5f / (0.001f * 0.001f);
    float breg[8] = {0.f,0.f,0.f,0.f,0.f,0.f,0.f,0.f};

    // ---- doc indices: wave's 4 chunks, own row = l15
    int dix[4];
    #pragma unroll
    for (int c = 0; c < 4; ++c) {
        int di = didx[b * D_LEN + w * 64 + c * 16 + l15];
        dix[c] = min(max(di, 0), V_SIZE - 1);
    }

    half8_t bh[4], bl[4];
    float rnd;

    // convert helper: 8x float4 (k-slices s*32+quad*8) -> B frags + own-row norm
    auto convert = [&](const float4* v) {
        float ss = 0.f;
        #pragma unroll
        for (int s = 0; s < 4; ++s) {
            float f[8] = {v[2*s].x, v[2*s].y, v[2*s].z, v[2*s].w,
                          v[2*s+1].x, v[2*s+1].y, v[2*s+1].z, v[2*s+1].w};
            half8_t h, l;
            #pragma unroll
            for (int j = 0; j < 8; ++j) {
                ss = fmaf(f[j], f[j], ss);
                _Float16 hh = (_Float16)f[j];
                h[j] = hh; l[j] = (_Float16)(f[j] - (float)hh);
            }
            bh[s] = h; bl[s] = l;
        }
        ss += __shfl_xor(ss, 16);   // quad bit 0
        ss += __shfl_xor(ss, 32);   // quad bit 1
        rnd = 1.0f / fmaxf(sqrtf(ss), 1e-8f);
    };

    // prologue: chunk 0
    {
        const float4* dr = (const float4*)(emb + (size_t)dix[0] * E_DIM) + quad * 2;
        float4 cur[8];
        #pragma unroll
        for (int s = 0; s < 4; ++s) { cur[2*s] = dr[s*8]; cur[2*s+1] = dr[s*8+1]; }
        convert(cur);
    }

    // ---- barrier-free doc loop: 4 chunks of 16 docs
    #pragma unroll
    for (int c = 0; c < 4; ++c) {
        float4 nx[8];
        if (c < 3) {
            const float4* dr = (const float4*)(emb + (size_t)dix[c+1] * E_DIM) + quad * 2;
            #pragma unroll
            for (int s = 0; s < 4; ++s) { nx[2*s] = dr[s*8]; nx[2*s+1] = dr[s*8+1]; }
        }

        float4_t acc0 = {0.f,0.f,0.f,0.f}, acc1 = {0.f,0.f,0.f,0.f};
        #pragma unroll
        for (int s = 0; s < 4; ++s) {
            half8_t a0h = AfH[0][s][lane], a0l = AfL[0][s][lane];
            half8_t a1h = AfH[1][s][lane], a1l = AfL[1][s][lane];
            acc0 = __builtin_amdgcn_mfma_f32_16x16x32_f16(a0h, bh[s], acc0, 0, 0, 0);
            acc1 = __builtin_amdgcn_mfma_f32_16x16x32_f16(a1h, bh[s], acc1, 0, 0, 0);
            acc0 = __builtin_amdgcn_mfma_f32_16x16x32_f16(a0l, bh[s], acc0, 0, 0, 0);
            acc1 = __builtin_amdgcn_mfma_f32_16x16x32_f16(a1l, bh[s], acc1, 0, 0, 0);
            acc0 = __builtin_amdgcn_mfma_f32_16x16x32_f16(a0h, bl[s], acc0, 0, 0, 0);
            acc1 = __builtin_amdgcn_mfma_f32_16x16x32_f16(a1h, bl[s], acc1, 0, 0, 0);
        }

        // epilogue: mm -> broad reg-accum + nearest sharp bin atomic
        #pragma unroll
        for (int qt = 0; qt < 2; ++qt) {
            const float4_t acc = qt ? acc1 : acc0;
            #pragma unroll
            for (int r = 0; r < 4; ++r) {
                const float mm = acc[r] * rnqv[qt*4 + r] * rnd;
                const float x0 = mm + 0.95f;
                breg[qt*4 + r] += __expf(x0 * x0 * cc0);
                float g = rintf((mm + 0.85f) * 10.f);
                g = fminf(fmaxf(g, 0.f), 18.f);
                float mu = fmaf(g, 0.1f, -0.85f);
                int ks = (int)g + 1;
                if (mm > 0.975f) { mu = 1.0f; ks = 20; }
                const float xs = mm - mu;
                const float es = __expf(xs * xs * ccs);
                if (es > 0.f) atomicAdd(&phis[qt*16 + quad*4 + r][ks], es);
            }
        }

        if (c < 3) convert(nx);   // next chunk's frags + rnd (after epilogue used rnd)
    }

    // ---- broad-bin: reduce across the 16 lanes sharing each q
    #pragma unroll
    for (int i = 0; i < 8; ++i) {
        float v = breg[i];
        v += __shfl_xor(v, 1, 16);
        v += __shfl_xor(v, 2, 16);
        v += __shfl_xor(v, 4, 16);
        v += __shfl_xor(v, 8, 16);
        if (l15 == 0) atomicAdd(&phis[(i >> 2) * 16 + quad * 4 + (i & 3)][0], v);
    }
    __syncthreads();

    // ---- ko[k] = sum_q log1p(phis[q][k])
    for (int p = t; p < K_NUM * Q_LEN; p += 256) {
        const int q = p & 31;
        const int k = p >> 5;
        float l = log1pf(phis[q][k]);
        l += __shfl_xor(l, 1, 32);
        l += __shfl_xor(l, 2, 32);
        l += __shfl_xor(l, 4, 32);
        l += __shfl_xor(l, 8, 32);
        l += __shfl_xor(l, 16, 32);
        if (q == 0) ko[k] = l;
    }
    __syncthreads();

    // ---- MLP 21 -> 10 -> 5 -> 1 (thread 0)
    if (t == 0) {
        float x1v[10];
        #pragma unroll
        for (int i = 0; i < 10; ++i) {
            float s = b1[i];
            for (int k = 0; k < K_NUM; ++k) {
                float v = ko[k] > 0.f ? ko[k] : 0.f;
                s = fmaf(v, w1[k * 10 + i], s);
            }
            x1v[i] = s;
        }
        float x2v[5];
        #pragma unroll
        for (int i = 0; i < 5; ++i) {
            float s = b2[i];
            #pragma unroll
            for (int k = 0; k < 10; ++k) {
                float v = x1v[k] > 0.f ? x1v[k] : 0.f;
                s = fmaf(v, w2[k * 5 + i], s);
            }
            x2v[i] = s;
        }
        float s3 = b3[0];
        #pragma unroll
        for (int k = 0; k < 5; ++k) {
            float v = x2v[k] > 0.f ? x2v[k] : 0.f;
            s3 = fmaf(v, w3[k], s3);
        }
        logits[pair * B_SIZE + b] = s3;
    }
}

__global__ void knrm_final(const float* __restrict__ logits, float* __restrict__ out)
{
    const int b = blockIdx.x * blockDim.x + threadIdx.x;
    if (b < B_SIZE) {
        const float dl = logits[b] - logits[B_SIZE + b];
        out[b] = 1.0f / (1.0f + __expf(-dl));
    }
}

extern "C" void kernel_launch(void* const* d_in, const int* in_sizes, int n_in,
                              void* d_out, int out_size, void* d_ws, size_t ws_size,
                              hipStream_t stream)
{
    const float* emb = (const float*)d_in[0];
    const float* w1  = (const float*)d_in[1];
    const float* b1  = (const float*)d_in[2];
    const float* w2  = (const float*)d_in[3];
    const float* b2  = (const float*)d_in[4];
    const float* w3  = (const float*)d_in[5];
    const float* b3  = (const float*)d_in[6];
    const int*   q1  = (const int*)d_in[7];
    const int*   d1  = (const int*)d_in[8];
    const int*   q2  = (const int*)d_in[9];
    const int*   d2  = (const int*)d_in[10];

    float* logits = (float*)d_ws;          // [2][B_SIZE]
    float* out    = (float*)d_out;         // [B_SIZE]

    dim3 grid(B_SIZE, 2);
    knrm_main<<<grid, 256, 0, stream>>>(emb, q1, d1, q2, d2,
                                        w1, b1, w2, b2, w3, b3, logits);
    knrm_final<<<(B_SIZE + 255) / 256, 256, 0, stream>>>(logits, out);
}